// Round 1
// baseline (632.895 us; speedup 1.0000x reference)
//
#include <hip/hip_runtime.h>
#include <cstdint>
#include <cstddef>

// MossVLSelfAttention fused pipeline, MI355X baseline (round 1).
// Strategy: all matmuls via bf16x3 split-precision MFMA (err ~1e-4 rel).
// Pipeline: trig table -> bf16 hi/lo splits (weights transposed) ->
//   QKV GEMM -> RMSNorm+RoPE+split -> causal flash attention -> out GEMM.
// Workspace layout (byte offsets, needs ~146 MB):
//   0   hid_hi[T][2048]      8M   hid_lo
//   16M wqkvT_hi[4096][2048] 32M  wqkvT_lo
//   48M woT_hi[2048][2048]   56M  woT_lo
//   64M qkv_f32[T][4096]
//   96M q_hi[T][16][128]     104M q_lo
//   112M k_hi[T][8][128]     116M k_lo
//   120M vT_hi[8][128][T]    124M vT_lo
//   128M attn_hi[T][2048]    136M attn_lo
//   144M trig[T][64] float2

#define C_NH 16
#define C_NKV 8
#define C_DH 128
#define C_HID 2048
#define C_NQKV 4096

typedef unsigned short u16;
typedef __attribute__((ext_vector_type(8))) short short8;
typedef __attribute__((ext_vector_type(4))) float f32x4;

__device__ __forceinline__ u16 f2bf(float x) {
  uint32_t u = __float_as_uint(x);
  u += 0x7FFFu + ((u >> 16) & 1u);   // round-to-nearest-even
  return (u16)(u >> 16);
}
__device__ __forceinline__ float bf2f(u16 h) {
  return __uint_as_float(((uint32_t)h) << 16);
}
__device__ __forceinline__ void bsplit(float x, u16& hi, u16& lo) {
  u16 h = f2bf(x);
  hi = h;
  lo = f2bf(x - bf2f(h));             // residual capture: ~16 mantissa bits total
}

// ---------------- trig table: tab[t][j] = (cos, sin)(pos[t] * theta^(-j/64)) ----
__global__ void k_trig(const int* __restrict__ pos, float2* __restrict__ tab) {
  int t = blockIdx.x;
  int j = threadIdx.x;                // 64 threads
  float inv = 1.0f / powf(1.0e6f, (float)j * (1.0f / 64.0f));
  float ang = (float)pos[t] * inv;
  tab[t * 64 + j] = make_float2(cosf(ang), sinf(ang));
}

// ---------------- plain split: f32[n] -> hi/lo bf16 ---------------------------
struct __align__(8) U4 { u16 a, b, c, d; };

__global__ void k_split(const float* __restrict__ in, u16* __restrict__ hi,
                        u16* __restrict__ lo, int n) {
  int i = (blockIdx.x * 256 + threadIdx.x) * 4;
  if (i >= n) return;
  float4 x = *(const float4*)(in + i);
  U4 hv, lv;
  bsplit(x.x, hv.a, lv.a);
  bsplit(x.y, hv.b, lv.b);
  bsplit(x.z, hv.c, lv.c);
  bsplit(x.w, hv.d, lv.d);
  *(U4*)(hi + i) = hv;
  *(U4*)(lo + i) = lv;
}

// ---------------- split + transpose: in[K][N] -> hi/lo[N][K] ------------------
__global__ void k_split_tr(const float* __restrict__ in, u16* __restrict__ hi,
                           u16* __restrict__ lo, int K, int N) {
  __shared__ float t[64][65];
  const int kb = blockIdx.y * 64, nb = blockIdx.x * 64;
  const int tid = threadIdx.x;
  for (int i = tid; i < 4096; i += 256) {
    int r = i >> 6, c = i & 63;
    t[r][c] = in[(size_t)(kb + r) * N + nb + c];
  }
  __syncthreads();
  for (int i = tid; i < 4096; i += 256) {
    int r = i >> 6, c = i & 63;       // r = n-local, c = k-local
    u16 h, l;
    bsplit(t[c][r], h, l);
    size_t o = (size_t)(nb + r) * K + kb + c;
    hi[o] = h;
    lo[o] = l;
  }
}

// ---------------- bf16x3 GEMM: C[M][N] = A[M][K] * B^T[N][K] ------------------
// 128x128 tile, 4 waves (64x64 each), BK=32, double-buffered LDS,
// reg-staged with load-early / write-late (T14) around the MFMA block.
__global__ __launch_bounds__(256, 2)
void k_gemm_x3(const u16* __restrict__ Ah, const u16* __restrict__ Al,
               const u16* __restrict__ Bh, const u16* __restrict__ Bl,
               float* __restrict__ C, int M, int N, int K) {
  __shared__ u16 lds[2][4][128 * 32];   // [buf][Ah,Al,Bh,Bl][128 rows x 32 k]
  const int tid = threadIdx.x;
  const int lane = tid & 63;
  const int wv = tid >> 6;
  const int wr = wv >> 1, wc = wv & 1;
  const int mb = blockIdx.y * 128, nb = blockIdx.x * 128;
  const int ra = lane & 15, ko = (lane >> 4) * 8;

  f32x4 acc[4][4] = {};
  short8 tAh[2], tAl[2], tBh[2], tBl[2];

  auto load_tile = [&](int kt) {
    const int kb = kt * 32;
#pragma unroll
    for (int i = 0; i < 2; ++i) {
      int c = i * 256 + tid;
      int row = c >> 2;
      int off = (c & 3) * 8;
      tAh[i] = *(const short8*)(Ah + (size_t)(mb + row) * K + kb + off);
      tAl[i] = *(const short8*)(Al + (size_t)(mb + row) * K + kb + off);
      tBh[i] = *(const short8*)(Bh + (size_t)(nb + row) * K + kb + off);
      tBl[i] = *(const short8*)(Bl + (size_t)(nb + row) * K + kb + off);
    }
  };
  auto write_tile = [&](int buf) {
#pragma unroll
    for (int i = 0; i < 2; ++i) {
      int e = (i * 256 + tid) * 8;
      *(short8*)&lds[buf][0][e] = tAh[i];
      *(short8*)&lds[buf][1][e] = tAl[i];
      *(short8*)&lds[buf][2][e] = tBh[i];
      *(short8*)&lds[buf][3][e] = tBl[i];
    }
  };

  const int nk = K >> 5;
  load_tile(0);
  write_tile(0);
  for (int kt = 0; kt < nk; ++kt) {
    const int buf = kt & 1;
    __syncthreads();                          // buf ready for everyone
    if (kt + 1 < nk) load_tile(kt + 1);       // issue global loads early
    short8 a_h[4], a_l[4], b_h[4], b_l[4];
#pragma unroll
    for (int m = 0; m < 4; ++m) {
      int r = (wr * 64 + m * 16 + ra) * 32 + ko;
      a_h[m] = *(const short8*)&lds[buf][0][r];
      a_l[m] = *(const short8*)&lds[buf][1][r];
    }
#pragma unroll
    for (int n = 0; n < 4; ++n) {
      int r = (wc * 64 + n * 16 + ra) * 32 + ko;
      b_h[n] = *(const short8*)&lds[buf][2][r];
      b_l[n] = *(const short8*)&lds[buf][3][r];
    }
#pragma unroll
    for (int m = 0; m < 4; ++m)
#pragma unroll
      for (int n = 0; n < 4; ++n) {
        acc[m][n] = __builtin_amdgcn_mfma_f32_16x16x32_bf16(a_h[m], b_h[n], acc[m][n], 0, 0, 0);
        acc[m][n] = __builtin_amdgcn_mfma_f32_16x16x32_bf16(a_h[m], b_l[n], acc[m][n], 0, 0, 0);
        acc[m][n] = __builtin_amdgcn_mfma_f32_16x16x32_bf16(a_l[m], b_h[n], acc[m][n], 0, 0, 0);
      }
    if (kt + 1 < nk) write_tile(buf ^ 1);     // ds_write after MFMAs (hide vmem)
  }
  const int cr = mb + wr * 64 + (lane >> 4) * 4;
  const int cc = nb + wc * 64 + ra;
#pragma unroll
  for (int m = 0; m < 4; ++m)
#pragma unroll
    for (int n = 0; n < 4; ++n)
#pragma unroll
      for (int r = 0; r < 4; ++r)
        C[(size_t)(cr + m * 16 + r) * N + cc + n * 16] = acc[m][n][r];
}

// ---------------- RMSNorm + RoPE + split (q,k) / split+transpose (v) ----------
// One wave per (t, head); heads 0..15 q, 16..23 k, 24..31 v.
__global__ void k_normrope(const float* __restrict__ qkv, const float2* __restrict__ tab,
                           const float* __restrict__ qw, const float* __restrict__ kw,
                           u16* __restrict__ Qh, u16* __restrict__ Ql,
                           u16* __restrict__ Kh, u16* __restrict__ Kl,
                           u16* __restrict__ Vh, u16* __restrict__ Vl, int T) {
  int gw = blockIdx.x * 4 + (threadIdx.x >> 6);
  if (gw >= T * 32) return;
  int lane = threadIdx.x & 63;
  int t = gw >> 5, hd = gw & 31;
  const float* src;
  if (hd < C_NH)             src = qkv + (size_t)t * C_NQKV + hd * C_DH;
  else if (hd < C_NH + C_NKV) src = qkv + (size_t)t * C_NQKV + C_NH * C_DH + (hd - C_NH) * C_DH;
  else                        src = qkv + (size_t)t * C_NQKV + (C_NH + C_NKV) * C_DH + (hd - C_NH - C_NKV) * C_DH;
  float x1 = src[lane], x2 = src[lane + 64];

  if (hd >= C_NH + C_NKV) {   // v: split + store transposed [8][128][T]
    int vh = hd - C_NH - C_NKV;
    u16 h, l;
    bsplit(x1, h, l);
    size_t o1 = ((size_t)vh * C_DH + lane) * T + t;
    Vh[o1] = h; Vl[o1] = l;
    bsplit(x2, h, l);
    size_t o2 = ((size_t)vh * C_DH + lane + 64) * T + t;
    Vh[o2] = h; Vl[o2] = l;
    return;
  }
  float ss = x1 * x1 + x2 * x2;
  ss += __shfl_xor(ss, 1, 64);
  ss += __shfl_xor(ss, 2, 64);
  ss += __shfl_xor(ss, 4, 64);
  ss += __shfl_xor(ss, 8, 64);
  ss += __shfl_xor(ss, 16, 64);
  ss += __shfl_xor(ss, 32, 64);
  float rms = rsqrtf(ss * (1.0f / 128.0f) + 1e-6f);
  const float* w = (hd < C_NH) ? qw : kw;
  float y1 = x1 * rms * w[lane];
  float y2 = x2 * rms * w[lane + 64];
  float2 cs = tab[t * 64 + lane];
  float o1 = y1 * cs.x - y2 * cs.y;
  float o2 = y2 * cs.x + y1 * cs.y;
  u16 h, l;
  if (hd < C_NH) {
    size_t o = ((size_t)t * C_NH + hd) * C_DH + lane;
    bsplit(o1, h, l); Qh[o] = h; Ql[o] = l;
    bsplit(o2, h, l); Qh[o + 64] = h; Ql[o + 64] = l;
  } else {
    int kh = hd - C_NH;
    size_t o = ((size_t)t * C_NKV + kh) * C_DH + lane;
    bsplit(o1, h, l); Kh[o] = h; Kl[o] = l;
    bsplit(o2, h, l); Kh[o + 64] = h; Kl[o + 64] = l;
  }
}

// ---------------- causal flash attention (GQA group=2), bf16x3 ----------------
// Grid (T/64, NH). Block 256 = 4 waves; wave owns 16 q-rows. KVBLK=32.
// K staged [32][136] (padded), V staged from global-transposed as [128][40].
__global__ __launch_bounds__(256, 2)
void k_flash(const u16* __restrict__ Qh, const u16* __restrict__ Ql,
             const u16* __restrict__ Kg_h, const u16* __restrict__ Kg_l,
             const u16* __restrict__ Vg_h, const u16* __restrict__ Vg_l,
             u16* __restrict__ Oh, u16* __restrict__ Ol, int T) {
  __shared__ u16 Ksh[32][136], Ksl[32][136];
  __shared__ u16 Vsh[128][40], Vsl[128][40];
  __shared__ u16 Psh[4][16][40], Psl[4][16][40];
  const int tid = threadIdx.x, lane = tid & 63, wv = tid >> 6;
  const int qt = blockIdx.x, h = blockIdx.y, hk = h >> 1;
  const int qb = qt * 64 + wv * 16;
  const int lm = lane & 15, lq = lane >> 4;

  // Q fragments held in registers for the whole kernel (A-frag layout).
  short8 qfh[4], qfl[4];
#pragma unroll
  for (int kc = 0; kc < 4; ++kc) {
    size_t o = ((size_t)(qb + lm) * C_NH + h) * C_DH + kc * 32 + lq * 8;
    qfh[kc] = *(const short8*)(Qh + o);
    qfl[kc] = *(const short8*)(Ql + o);
  }
  f32x4 o_acc[8] = {};
  float m_r[4], l_r[4];
#pragma unroll
  for (int r = 0; r < 4; ++r) { m_r[r] = -1e30f; l_r[r] = 0.f; }

  const float scale = 0.08838834764831845f;   // 1/sqrt(128)
  const int ntiles = 2 * qt + 2;
  for (int kt = 0; kt < ntiles; ++kt) {
    const int kvb = kt * 32;
    __syncthreads();                          // previous tile's LDS reads done
#pragma unroll
    for (int i = 0; i < 2; ++i) {             // stage K[32][128] and V^T[128][32]
      int c = i * 256 + tid;
      int krow = c >> 4, kko = (c & 15) * 8;
      size_t go = ((size_t)(kvb + krow) * C_NKV + hk) * C_DH + kko;
      *(short8*)&Ksh[krow][kko] = *(const short8*)(Kg_h + go);
      *(short8*)&Ksl[krow][kko] = *(const short8*)(Kg_l + go);
      int vd = c >> 2, vko = (c & 3) * 8;
      size_t gv = ((size_t)hk * C_DH + vd) * T + kvb + vko;
      *(short8*)&Vsh[vd][vko] = *(const short8*)(Vg_h + gv);
      *(short8*)&Vsl[vd][vko] = *(const short8*)(Vg_l + gv);
    }
    __syncthreads();

    // S = Q K^T (bf16x3)
    f32x4 s[2] = {};
#pragma unroll
    for (int kc = 0; kc < 4; ++kc) {
#pragma unroll
      for (int nb2 = 0; nb2 < 2; ++nb2) {
        short8 bh = *(const short8*)&Ksh[lm + 16 * nb2][kc * 32 + lq * 8];
        short8 bl = *(const short8*)&Ksl[lm + 16 * nb2][kc * 32 + lq * 8];
        s[nb2] = __builtin_amdgcn_mfma_f32_16x16x32_bf16(qfh[kc], bh, s[nb2], 0, 0, 0);
        s[nb2] = __builtin_amdgcn_mfma_f32_16x16x32_bf16(qfh[kc], bl, s[nb2], 0, 0, 0);
        s[nb2] = __builtin_amdgcn_mfma_f32_16x16x32_bf16(qfl[kc], bh, s[nb2], 0, 0, 0);
      }
    }

    // online softmax (fp32, per-row stats; rows live in lanes sharing lq)
#pragma unroll
    for (int r = 0; r < 4; ++r) {
      int qrow = qb + lq * 4 + r;
      float sv0 = (kvb + lm      <= qrow) ? s[0][r] * scale : -1e30f;
      float sv1 = (kvb + lm + 16 <= qrow) ? s[1][r] * scale : -1e30f;
      float pm = fmaxf(sv0, sv1);
      pm = fmaxf(pm, __shfl_xor(pm, 1, 16));
      pm = fmaxf(pm, __shfl_xor(pm, 2, 16));
      pm = fmaxf(pm, __shfl_xor(pm, 4, 16));
      pm = fmaxf(pm, __shfl_xor(pm, 8, 16));
      float mn = fmaxf(m_r[r], pm);
      float alpha = __expf(m_r[r] - mn);
      float p0 = __expf(sv0 - mn);
      float p1 = __expf(sv1 - mn);
      float ps = p0 + p1;
      ps += __shfl_xor(ps, 1, 16);
      ps += __shfl_xor(ps, 2, 16);
      ps += __shfl_xor(ps, 4, 16);
      ps += __shfl_xor(ps, 8, 16);
      l_r[r] = l_r[r] * alpha + ps;
      m_r[r] = mn;
#pragma unroll
      for (int jb = 0; jb < 8; ++jb) o_acc[jb][r] *= alpha;
      u16 ph, pl;
      bsplit(p0, ph, pl);
      Psh[wv][lq * 4 + r][lm] = ph;
      Psl[wv][lq * 4 + r][lm] = pl;
      bsplit(p1, ph, pl);
      Psh[wv][lq * 4 + r][lm + 16] = ph;
      Psl[wv][lq * 4 + r][lm + 16] = pl;
    }

    // O += P V (bf16x3; wave-local P through LDS, no barrier needed)
    short8 pah = *(const short8*)&Psh[wv][lm][lq * 8];
    short8 pal = *(const short8*)&Psl[wv][lm][lq * 8];
#pragma unroll
    for (int jb = 0; jb < 8; ++jb) {
      short8 vh = *(const short8*)&Vsh[lm + 16 * jb][lq * 8];
      short8 vl = *(const short8*)&Vsl[lm + 16 * jb][lq * 8];
      o_acc[jb] = __builtin_amdgcn_mfma_f32_16x16x32_bf16(pah, vh, o_acc[jb], 0, 0, 0);
      o_acc[jb] = __builtin_amdgcn_mfma_f32_16x16x32_bf16(pah, vl, o_acc[jb], 0, 0, 0);
      o_acc[jb] = __builtin_amdgcn_mfma_f32_16x16x32_bf16(pal, vh, o_acc[jb], 0, 0, 0);
    }
  }

  // epilogue: O /= l, split to bf16 hi/lo for the out-proj GEMM
#pragma unroll
  for (int r = 0; r < 4; ++r) {
    float inv = 1.0f / l_r[r];
    int qrow = qb + lq * 4 + r;
#pragma unroll
    for (int jb = 0; jb < 8; ++jb) {
      int d = lm + 16 * jb;
      float val = o_acc[jb][r] * inv;
      u16 hh, ll;
      bsplit(val, hh, ll);
      size_t oo = ((size_t)qrow * C_NH + h) * C_DH + d;
      Oh[oo] = hh;
      Ol[oo] = ll;
    }
  }
}

// ---------------- launch --------------------------------------------------------
extern "C" void kernel_launch(void* const* d_in, const int* in_sizes, int n_in,
                              void* d_out, int out_size, void* d_ws, size_t ws_size,
                              hipStream_t stream) {
  const int*   pos  = (const int*)d_in[0];
  const float* hid  = (const float*)d_in[1];
  const float* wqkv = (const float*)d_in[2];
  const float* qnw  = (const float*)d_in[3];
  const float* knw  = (const float*)d_in[4];
  const float* wo   = (const float*)d_in[5];
  float* out = (float*)d_out;
  const int T = in_sizes[0];                   // 2048

  char* ws = (char*)d_ws;
  const size_t MB = 1024 * 1024;
  u16*    hid_h = (u16*)(ws);
  u16*    hid_l = (u16*)(ws + 8 * MB);
  u16*    wq_h  = (u16*)(ws + 16 * MB);
  u16*    wq_l  = (u16*)(ws + 32 * MB);
  u16*    wo_h  = (u16*)(ws + 48 * MB);
  u16*    wo_l  = (u16*)(ws + 56 * MB);
  float*  qkv   = (float*)(ws + 64 * MB);
  u16*    q_h   = (u16*)(ws + 96 * MB);
  u16*    q_l   = (u16*)(ws + 104 * MB);
  u16*    k_h   = (u16*)(ws + 112 * MB);
  u16*    k_l   = (u16*)(ws + 116 * MB);
  u16*    v_h   = (u16*)(ws + 120 * MB);
  u16*    v_l   = (u16*)(ws + 124 * MB);
  u16*    at_h  = (u16*)(ws + 128 * MB);
  u16*    at_l  = (u16*)(ws + 136 * MB);
  float2* tab   = (float2*)(ws + 144 * MB);

  k_trig<<<T, 64, 0, stream>>>(pos, tab);
  k_split<<<(T * C_HID) / 1024, 256, 0, stream>>>(hid, hid_h, hid_l, T * C_HID);
  k_split_tr<<<dim3(C_NQKV / 64, C_HID / 64), 256, 0, stream>>>(wqkv, wq_h, wq_l, C_HID, C_NQKV);
  k_split_tr<<<dim3(C_HID / 64, C_HID / 64), 256, 0, stream>>>(wo, wo_h, wo_l, C_HID, C_HID);
  k_gemm_x3<<<dim3(C_NQKV / 128, T / 128), 256, 0, stream>>>(hid_h, hid_l, wq_h, wq_l, qkv, T, C_NQKV, C_HID);
  k_normrope<<<(T * 32) / 4, 256, 0, stream>>>(qkv, tab, qnw, knw, q_h, q_l, k_h, k_l, v_h, v_l, T);
  k_flash<<<dim3(T / 64, C_NH), 256, 0, stream>>>(q_h, q_l, k_h, k_l, v_h, v_l, at_h, at_l, T);
  k_gemm_x3<<<dim3(C_HID / 128, T / 128), 256, 0, stream>>>(at_h, at_l, wo_h, wo_l, out, T, C_HID, C_HID);
}